// Round 3
// baseline (247.131 us; speedup 1.0000x reference)
//
#include <hip/hip_runtime.h>
#include <hip/hip_bf16.h>

// attention_11269994185437: B=4, C=256, CQK=32, H=W=64 -> N=4096
// out = gamma * (V @ P) + x,  P[n,m] = softmax over m of S[n,m], S = Q^T K.
// Qt is pre-scaled by L2E so S' = L2E * S comes out of the MFMA directly.
// cbias[b][n] = -max(S') - log2(sum exp2(S'-max))  =>  E = exp2(S' + cbias).
// k_attn_out is n-split across blocks (occupancy!), partials combined by k_comb.

#define NB 4
#define CC 256
#define NN 4096
#define MSPLIT 4
#define L2E 1.44269504088896340f

typedef short  short4v  __attribute__((ext_vector_type(4)));
typedef short  short8v  __attribute__((ext_vector_type(8)));
typedef __bf16 bf16x8   __attribute__((ext_vector_type(8)));
typedef float  f32x4    __attribute__((ext_vector_type(4)));
typedef float  f32x16   __attribute__((ext_vector_type(16)));

static __device__ __forceinline__ unsigned short f2bf(float f) {
  union { __bf16 h; unsigned short u; } v; v.h = (__bf16)f; return v.u;
}

union FragU { short8v s; bf16x8 b; unsigned u[4]; };
union PackU { __bf16 h[8]; unsigned u[4]; };

static __device__ __forceinline__ bf16x8 ld_frag(const unsigned short* p) {
  FragU u; u.s = *(const short8v*)p; return u.b;
}

static __device__ __forceinline__ f32x16 zero16() {
  f32x16 v;
#pragma unroll
  for (int i = 0; i < 16; ++i) v[i] = 0.0f;
  return v;
}

static __device__ __forceinline__ f32x16 mfma32(bf16x8 a, bf16x8 b, f32x16 c) {
  return __builtin_amdgcn_mfma_f32_32x32x16_bf16(a, b, c, 0, 0, 0);
}

// ---------------- Kernel 1: QKV projection --------------------------------
__global__ __launch_bounds__(256) void k_proj(
    const float* __restrict__ x,
    const float* __restrict__ Wq, const float* __restrict__ bq,
    const float* __restrict__ Wk, const float* __restrict__ bk,
    const float* __restrict__ Wv, const float* __restrict__ bv,
    unsigned short* __restrict__ Qt, unsigned short* __restrict__ Kt,
    unsigned short* __restrict__ Vb)
{
  __shared__ unsigned short xs[64][268];   // xs[n_local][c]
  const int t = threadIdx.x;
  const int b = blockIdx.y;
  const int n0 = blockIdx.x * 64;
  const int w = t >> 6, l = t & 63, h = l >> 5, col = l & 31;

  const float* xb = x + (size_t)b * CC * NN;
  {
    const int c_off = t >> 4, nl = 4 * (t & 15);
#pragma unroll
    for (int c0 = 0; c0 < CC; c0 += 16) {
      int c = c0 + c_off;
      f32x4 v4 = *(const f32x4*)(xb + (size_t)c * NN + n0 + nl);
#pragma unroll
      for (int j = 0; j < 4; ++j) xs[nl + j][c] = f2bf(v4[j]);
    }
  }
  __syncthreads();

  for (int f = w; f < 10; f += 4) {
    const float* Wsrc; const float* bsrc; int rowbase; int mode;
    if (f == 0)      { Wsrc = Wq; bsrc = bq; rowbase = 0;            mode = 0; }
    else if (f == 1) { Wsrc = Wk; bsrc = bk; rowbase = 0;            mode = 1; }
    else             { Wsrc = Wv; bsrc = bv; rowbase = (f - 2) * 32; mode = 2; }

    f32x16 acc0 = zero16(), acc1 = zero16();
    const float* wr = Wsrc + (size_t)(rowbase + col) * CC + 8 * h;

#pragma unroll
    for (int k0 = 0; k0 < CC; k0 += 16) {
      f32x4 w0 = *(const f32x4*)(wr + k0);
      f32x4 w1 = *(const f32x4*)(wr + k0 + 4);
      FragU a;
#pragma unroll
      for (int j = 0; j < 4; ++j) { a.s[j] = (short)f2bf(w0[j]); a.s[4 + j] = (short)f2bf(w1[j]); }
      const unsigned short* p0 = &xs[col][k0 + 8 * h];
      const unsigned short* p1 = &xs[32 + col][k0 + 8 * h];
      FragU b0, b1;
      short4v t0a = *(const short4v*)p0, t0b = *(const short4v*)(p0 + 4);
      short4v t1a = *(const short4v*)p1, t1b = *(const short4v*)(p1 + 4);
#pragma unroll
      for (int j = 0; j < 4; ++j) {
        b0.s[j] = t0a[j]; b0.s[4 + j] = t0b[j];
        b1.s[j] = t1a[j]; b1.s[4 + j] = t1b[j];
      }
      acc0 = mfma32(a.b, b0.b, acc0);
      acc1 = mfma32(a.b, b1.b, acc1);
    }

#pragma unroll
    for (int nf = 0; nf < 2; ++nf) {
      f32x16 A = nf ? acc1 : acc0;
      const int n = n0 + 32 * nf + col;
#pragma unroll
      for (int q = 0; q < 4; ++q) {
        f32x4 bias4 = *(const f32x4*)(bsrc + rowbase + 8 * q + 4 * h);
        float vals[4];
#pragma unroll
        for (int i = 0; i < 4; ++i) vals[i] = A[4 * q + i] + bias4[i];
        if (mode == 2) {
#pragma unroll
          for (int i = 0; i < 4; ++i) {
            int c = rowbase + 8 * q + 4 * h + i;
            Vb[((size_t)b * CC + c) * NN + n] = f2bf(vals[i]);
          }
        } else {
          unsigned short* dst = (mode == 0) ? Qt : Kt;
          const float scale = (mode == 0) ? L2E : 1.0f;   // fold L2E into Q
          short4v s4;
#pragma unroll
          for (int i = 0; i < 4; ++i) s4[i] = (short)f2bf(vals[i] * scale);
          *(short4v*)(dst + ((size_t)b * NN + n) * 32 + 8 * q + 4 * h) = s4;
        }
      }
    }
  }
}

// ---------------- Kernel 2a: partial row stats (S' domain) ----------------
__global__ __launch_bounds__(64) void k_rowstats_part(
    const unsigned short* __restrict__ Qt, const unsigned short* __restrict__ Kt,
    float* __restrict__ pmax, float* __restrict__ psum)
{
  const int l = threadIdx.x, h = l >> 5, col = l & 31;
  const int b = blockIdx.y;
  const int n0 = blockIdx.x * 32;
  const int mbase = blockIdx.z * (NN / MSPLIT);
  const unsigned short* Qb = Qt + (size_t)b * NN * 32;
  const unsigned short* Kb = Kt + (size_t)b * NN * 32;

  bf16x8 aq0 = ld_frag(Qb + (size_t)(n0 + col) * 32 + 8 * h);
  bf16x8 aq1 = ld_frag(Qb + (size_t)(n0 + col) * 32 + 16 + 8 * h);

  float mx[16];
#pragma unroll
  for (int r = 0; r < 16; ++r) mx[r] = -3.4e38f;

  for (int m0 = mbase; m0 < mbase + NN / MSPLIT; m0 += 32) {
    bf16x8 bk0 = ld_frag(Kb + (size_t)(m0 + col) * 32 + 8 * h);
    bf16x8 bk1 = ld_frag(Kb + (size_t)(m0 + col) * 32 + 16 + 8 * h);
    f32x16 S = zero16();
    S = mfma32(aq0, bk0, S);
    S = mfma32(aq1, bk1, S);
#pragma unroll
    for (int r = 0; r < 16; ++r) mx[r] = fmaxf(mx[r], S[r]);
  }
#pragma unroll
  for (int off = 1; off < 32; off <<= 1)
#pragma unroll
    for (int r = 0; r < 16; ++r) mx[r] = fmaxf(mx[r], __shfl_xor(mx[r], off));

  float sm[16];
#pragma unroll
  for (int r = 0; r < 16; ++r) sm[r] = 0.0f;

  for (int m0 = mbase; m0 < mbase + NN / MSPLIT; m0 += 32) {
    bf16x8 bk0 = ld_frag(Kb + (size_t)(m0 + col) * 32 + 8 * h);
    bf16x8 bk1 = ld_frag(Kb + (size_t)(m0 + col) * 32 + 16 + 8 * h);
    f32x16 S = zero16();
    S = mfma32(aq0, bk0, S);
    S = mfma32(aq1, bk1, S);
#pragma unroll
    for (int r = 0; r < 16; ++r) sm[r] += __builtin_amdgcn_exp2f(S[r] - mx[r]);
  }
#pragma unroll
  for (int off = 1; off < 32; off <<= 1)
#pragma unroll
    for (int r = 0; r < 16; ++r) sm[r] += __shfl_xor(sm[r], off);

  if (col == 0) {
    const size_t base = ((size_t)b * MSPLIT + blockIdx.z) * NN;
#pragma unroll
    for (int r = 0; r < 16; ++r) {
      int n = n0 + (r & 3) + 8 * (r >> 2) + 4 * h;
      pmax[base + n] = mx[r];
      psum[base + n] = sm[r];
    }
  }
}

// ---------------- Kernel 2b: combine -> cbias = -max' - log2(sum) ---------
__global__ __launch_bounds__(256) void k_statfin(
    const float* __restrict__ pmax, const float* __restrict__ psum,
    float* __restrict__ cbias)
{
  const int i = blockIdx.x * 256 + threadIdx.x;
  const int b = i >> 12, n = i & (NN - 1);
  float pm[MSPLIT], ps[MSPLIT];
#pragma unroll
  for (int s = 0; s < MSPLIT; ++s) {
    pm[s] = pmax[((size_t)b * MSPLIT + s) * NN + n];
    ps[s] = psum[((size_t)b * MSPLIT + s) * NN + n];
  }
  float gmax = pm[0];
#pragma unroll
  for (int s = 1; s < MSPLIT; ++s) gmax = fmaxf(gmax, pm[s]);
  float gsum = 0.0f;
#pragma unroll
  for (int s = 0; s < MSPLIT; ++s) gsum += ps[s] * __builtin_amdgcn_exp2f(pm[s] - gmax);
  cbias[i] = -gmax - __builtin_amdgcn_logf(gsum);
}

// ---------------- Kernel 3: V @ E (n-split partials) ----------------------
// grid 256*nsplit blocks (XCD-swizzled), 4 waves. Wave: ch=w&1 (128 c), mf=w>>1.
// pout != nullptr: write f32 partial [ns][b][c][m]. pout == nullptr: direct
// out = g*acc + x (nsplit must be 1).
__global__ __launch_bounds__(256, 4) void k_attn_out(
    const unsigned short* __restrict__ Qt, const unsigned short* __restrict__ Kt,
    const unsigned short* __restrict__ Vb,
    const float* __restrict__ cbias,
    const float* __restrict__ x, const float* __restrict__ gamma,
    float* __restrict__ out, float* __restrict__ pout,
    int nsplit, int nlen)
{
  const int wg = (int)blockIdx.x;
  const int chunk = (int)gridDim.x >> 3;           // blocks per XCD (bijective)
  const int id2 = (wg & 7) * chunk + (wg >> 3);
  const int per_b = 64 * nsplit;
  const int b = id2 / per_b;
  const int rem = id2 - b * per_b;
  const int ns = rem >> 6;
  const int m0 = (rem & 63) * 64;
  const int nbeg = ns * nlen;

  const int t = threadIdx.x;
  const int w = t >> 6, l = t & 63, h = l >> 5, col = l & 31;
  const int ch = w & 1, mf = w >> 1;
  const int cbase = 128 * ch;
  const int m = m0 + 32 * mf + col;

  const unsigned short* Qb  = Qt + (size_t)b * NN * 32;
  const unsigned short* Kb  = Kt + (size_t)b * NN * 32;
  const unsigned short* Vbb = Vb + (size_t)b * CC * NN;
  const float* cb = cbias + (size_t)b * NN;

  bf16x8 bk0 = ld_frag(Kb + (size_t)m * 32 + 8 * h);
  bf16x8 bk1 = ld_frag(Kb + (size_t)m * 32 + 16 + 8 * h);

  const unsigned short* vr0 = Vbb + (size_t)(cbase + col) * NN;
  const unsigned short* vr1 = vr0 + (size_t)32 * NN;
  const unsigned short* vr2 = vr1 + (size_t)32 * NN;
  const unsigned short* vr3 = vr2 + (size_t)32 * NN;

  f32x16 acc[4];
#pragma unroll
  for (int cf = 0; cf < 4; ++cf) acc[cf] = zero16();

  for (int nn = nbeg; nn < nbeg + nlen; nn += 32) {
    bf16x8 aq0 = ld_frag(Qb + (size_t)(nn + col) * 32 + 8 * h);
    bf16x8 aq1 = ld_frag(Qb + (size_t)(nn + col) * 32 + 16 + 8 * h);
    f32x16 S = zero16();
    S = mfma32(aq0, bk0, S);
    S = mfma32(aq1, bk1, S);

    // E = exp2(S' + cbias[n]); pack to bf16
    PackU p0, p1;
#pragma unroll
    for (int q = 0; q < 4; ++q) {
      f32x4 cb4 = *(const f32x4*)(cb + nn + 8 * q + 4 * h);
#pragma unroll
      for (int i = 0; i < 4; ++i) {
        float e = __builtin_amdgcn_exp2f(S[4 * q + i] + cb4[i]);
        if (q < 2) p0.h[4 * q + i] = (__bf16)e;
        else       p1.h[4 * (q - 2) + i] = (__bf16)e;
      }
    }
    // relayout: swap(u[0],u[2]) -> (W0,W2); swap(u[1],u[3]) -> (W1,W3)
    // v_permlane32_swap a,c : a' = {a.lo, c.lo}, c' = {a.hi, c.hi}
    unsigned e00 = p0.u[0], e02 = p0.u[2];
    unsigned e01 = p0.u[1], e03 = p0.u[3];
    unsigned e10 = p1.u[0], e12 = p1.u[2];
    unsigned e11 = p1.u[1], e13 = p1.u[3];
    asm("v_permlane32_swap_b32 %0, %1" : "+v"(e00), "+v"(e02));
    asm("v_permlane32_swap_b32 %0, %1" : "+v"(e01), "+v"(e03));
    asm("v_permlane32_swap_b32 %0, %1" : "+v"(e10), "+v"(e12));
    asm("v_permlane32_swap_b32 %0, %1" : "+v"(e11), "+v"(e13));
    FragU be0, be1;
    be0.u[0] = e00; be0.u[1] = e01; be0.u[2] = e02; be0.u[3] = e03;
    be1.u[0] = e10; be1.u[1] = e11; be1.u[2] = e12; be1.u[3] = e13;

    bf16x8 av;
    av = ld_frag(vr0 + nn + 8 * h);      acc[0] = mfma32(av, be0.b, acc[0]);
    av = ld_frag(vr0 + nn + 16 + 8 * h); acc[0] = mfma32(av, be1.b, acc[0]);
    av = ld_frag(vr1 + nn + 8 * h);      acc[1] = mfma32(av, be0.b, acc[1]);
    av = ld_frag(vr1 + nn + 16 + 8 * h); acc[1] = mfma32(av, be1.b, acc[1]);
    av = ld_frag(vr2 + nn + 8 * h);      acc[2] = mfma32(av, be0.b, acc[2]);
    av = ld_frag(vr2 + nn + 16 + 8 * h); acc[2] = mfma32(av, be1.b, acc[2]);
    av = ld_frag(vr3 + nn + 8 * h);      acc[3] = mfma32(av, be0.b, acc[3]);
    av = ld_frag(vr3 + nn + 16 + 8 * h); acc[3] = mfma32(av, be1.b, acc[3]);
  }

  if (pout) {
    float* pb = pout + ((size_t)ns * NB + b) * CC * NN;
#pragma unroll
    for (int cf = 0; cf < 4; ++cf)
#pragma unroll
      for (int r = 0; r < 16; ++r) {
        int c = cbase + 32 * cf + (r & 3) + 8 * (r >> 2) + 4 * h;
        pb[(size_t)c * NN + m] = acc[cf][r];
      }
  } else {
    const float g = gamma[0];
#pragma unroll
    for (int cf = 0; cf < 4; ++cf)
#pragma unroll
      for (int r = 0; r < 16; ++r) {
        int c = cbase + 32 * cf + (r & 3) + 8 * (r >> 2) + 4 * h;
        size_t idx = ((size_t)b * CC + c) * NN + m;
        out[idx] = g * acc[cf][r] + x[idx];
      }
  }
}

// ---------------- Kernel 4: combine partials ------------------------------
__global__ __launch_bounds__(256) void k_comb(
    const float* __restrict__ pout, const float* __restrict__ x,
    const float* __restrict__ gamma, float* __restrict__ out, int nsplit)
{
  const size_t STRIDE = (size_t)NB * CC * NN;
  const size_t i = ((size_t)blockIdx.x * 256 + threadIdx.x) * 4;
  f32x4 s = *(const f32x4*)(pout + i);
  for (int ns = 1; ns < nsplit; ++ns) {
    f32x4 p = *(const f32x4*)(pout + ns * STRIDE + i);
#pragma unroll
    for (int j = 0; j < 4; ++j) s[j] += p[j];
  }
  const float g = gamma[0];
  f32x4 xv = *(const f32x4*)(x + i);
  f32x4 o;
#pragma unroll
  for (int j = 0; j < 4; ++j) o[j] = g * s[j] + xv[j];
  *(f32x4*)(out + i) = o;
}

// ---------------- launch ---------------------------------------------------
extern "C" void kernel_launch(void* const* d_in, const int* in_sizes, int n_in,
                              void* d_out, int out_size, void* d_ws, size_t ws_size,
                              hipStream_t stream) {
  const float* x     = (const float*)d_in[0];
  const float* Wq    = (const float*)d_in[1];
  const float* bq    = (const float*)d_in[2];
  const float* Wk    = (const float*)d_in[3];
  const float* bk    = (const float*)d_in[4];
  const float* Wv    = (const float*)d_in[5];
  const float* bv    = (const float*)d_in[6];
  const float* gamma = (const float*)d_in[7];
  float* out = (float*)d_out;

  char* ws = (char*)d_ws;
  unsigned short* Qt = (unsigned short*)(ws);                      // 1 MB
  unsigned short* Kt = (unsigned short*)(ws + (1u << 20));         // 1 MB
  unsigned short* Vb = (unsigned short*)(ws + (2u << 20));         // 8 MB
  float* pmax  = (float*)(ws + (10u << 20));                       // 256 KB
  float* psum  = (float*)(ws + (10u << 20) + (1u << 18));          // 256 KB
  float* cbias = (float*)(ws + (10u << 20) + (2u << 18));          // 64 KB
  const size_t POUT_OFF = (11u << 20);
  float* pout = (float*)(ws + POUT_OFF);
  const size_t PART_BYTES = (size_t)NB * CC * NN * 4;              // 16 MB

  int nsplit = 1;
  if (ws_size >= POUT_OFF + 4 * PART_BYTES)      nsplit = 4;
  else if (ws_size >= POUT_OFF + 2 * PART_BYTES) nsplit = 2;

  k_proj<<<dim3(NN / 64, NB), 256, 0, stream>>>(x, Wq, bq, Wk, bk, Wv, bv, Qt, Kt, Vb);
  k_rowstats_part<<<dim3(NN / 32, NB, MSPLIT), 64, 0, stream>>>(Qt, Kt, pmax, psum);
  k_statfin<<<dim3(NB * NN / 256), 256, 0, stream>>>(pmax, psum, cbias);

  if (nsplit > 1) {
    k_attn_out<<<dim3(256 * nsplit), 256, 0, stream>>>(
        Qt, Kt, Vb, cbias, x, gamma, out, pout, nsplit, NN / nsplit);
    k_comb<<<dim3(NB * CC * NN / 1024), 256, 0, stream>>>(pout, x, gamma, out, nsplit);
  } else {
    k_attn_out<<<dim3(256), 256, 0, stream>>>(
        Qt, Kt, Vb, cbias, x, gamma, out, nullptr, 1, NN);
  }
}

// Round 4
// 222.616 us; speedup vs baseline: 1.1101x; 1.1101x over previous
//
#include <hip/hip_runtime.h>
#include <hip/hip_bf16.h>

// attention_11269994185437: B=4, C=256, CQK=32, H=W=64 -> N=4096
// out = gamma * (V @ P) + x,  P[n,m] = softmax over m of S[n,m], S = Q^T K.
// Qt is pre-scaled by L2E so S' = L2E * S comes out of the MFMA directly.
// cbias[b][n] = -max(S') - log2(sum exp2(S'-max))  =>  E = exp2(S' + cbias).
// k_attn_out: n-split=2 for occupancy, register-pipelined (Q prefetch, early V).

#define NB 4
#define CC 256
#define NN 4096
#define MSPLIT 4
#define L2E 1.44269504088896340f

typedef short  short4v  __attribute__((ext_vector_type(4)));
typedef short  short8v  __attribute__((ext_vector_type(8)));
typedef __bf16 bf16x8   __attribute__((ext_vector_type(8)));
typedef float  f32x4    __attribute__((ext_vector_type(4)));
typedef float  f32x16   __attribute__((ext_vector_type(16)));

static __device__ __forceinline__ unsigned short f2bf(float f) {
  union { __bf16 h; unsigned short u; } v; v.h = (__bf16)f; return v.u;
}

union FragU { short8v s; bf16x8 b; unsigned u[4]; };
union PackU { __bf16 h[8]; unsigned u[4]; };

static __device__ __forceinline__ bf16x8 ld_frag(const unsigned short* p) {
  FragU u; u.s = *(const short8v*)p; return u.b;
}

static __device__ __forceinline__ f32x16 zero16() {
  f32x16 v;
#pragma unroll
  for (int i = 0; i < 16; ++i) v[i] = 0.0f;
  return v;
}

static __device__ __forceinline__ f32x16 mfma32(bf16x8 a, bf16x8 b, f32x16 c) {
  return __builtin_amdgcn_mfma_f32_32x32x16_bf16(a, b, c, 0, 0, 0);
}

// ---------------- Kernel 1: QKV projection --------------------------------
// grid (N/32, B), block 256 (4 waves), 32-n tile -> 2 blocks/CU.
__global__ __launch_bounds__(256) void k_proj(
    const float* __restrict__ x,
    const float* __restrict__ Wq, const float* __restrict__ bq,
    const float* __restrict__ Wk, const float* __restrict__ bk,
    const float* __restrict__ Wv, const float* __restrict__ bv,
    unsigned short* __restrict__ Qt, unsigned short* __restrict__ Kt,
    unsigned short* __restrict__ Vb)
{
  __shared__ unsigned short xs[32][268];   // xs[n_local][c]
  const int t = threadIdx.x;
  const int b = blockIdx.y;
  const int n0 = blockIdx.x * 32;
  const int w = t >> 6, l = t & 63, h = l >> 5, col = l & 31;

  const float* xb = x + (size_t)b * CC * NN;
  {
    const int c_off = t >> 3, nl = 4 * (t & 7);   // 32 c-rows per pass, 8 lanes/row
#pragma unroll
    for (int c0 = 0; c0 < CC; c0 += 32) {
      int c = c0 + c_off;
      f32x4 v4 = *(const f32x4*)(xb + (size_t)c * NN + n0 + nl);
#pragma unroll
      for (int j = 0; j < 4; ++j) xs[nl + j][c] = f2bf(v4[j]);
    }
  }
  __syncthreads();

  for (int f = w; f < 10; f += 4) {
    const float* Wsrc; const float* bsrc; int rowbase; int mode;
    if (f == 0)      { Wsrc = Wq; bsrc = bq; rowbase = 0;            mode = 0; }
    else if (f == 1) { Wsrc = Wk; bsrc = bk; rowbase = 0;            mode = 1; }
    else             { Wsrc = Wv; bsrc = bv; rowbase = (f - 2) * 32; mode = 2; }

    f32x16 acc0 = zero16();
    const float* wr = Wsrc + (size_t)(rowbase + col) * CC + 8 * h;

#pragma unroll
    for (int k0 = 0; k0 < CC; k0 += 16) {
      f32x4 w0 = *(const f32x4*)(wr + k0);
      f32x4 w1 = *(const f32x4*)(wr + k0 + 4);
      FragU a;
#pragma unroll
      for (int j = 0; j < 4; ++j) { a.s[j] = (short)f2bf(w0[j]); a.s[4 + j] = (short)f2bf(w1[j]); }
      const unsigned short* p0 = &xs[col][k0 + 8 * h];
      FragU b0;
      short4v t0a = *(const short4v*)p0, t0b = *(const short4v*)(p0 + 4);
#pragma unroll
      for (int j = 0; j < 4; ++j) { b0.s[j] = t0a[j]; b0.s[4 + j] = t0b[j]; }
      acc0 = mfma32(a.b, b0.b, acc0);
    }

    const int n = n0 + col;
#pragma unroll
    for (int q = 0; q < 4; ++q) {
      f32x4 bias4 = *(const f32x4*)(bsrc + rowbase + 8 * q + 4 * h);
      float vals[4];
#pragma unroll
      for (int i = 0; i < 4; ++i) vals[i] = acc0[4 * q + i] + bias4[i];
      if (mode == 2) {
#pragma unroll
        for (int i = 0; i < 4; ++i) {
          int c = rowbase + 8 * q + 4 * h + i;
          Vb[((size_t)b * CC + c) * NN + n] = f2bf(vals[i]);
        }
      } else {
        unsigned short* dst = (mode == 0) ? Qt : Kt;
        const float scale = (mode == 0) ? L2E : 1.0f;   // fold L2E into Q
        short4v s4;
#pragma unroll
        for (int i = 0; i < 4; ++i) s4[i] = (short)f2bf(vals[i] * scale);
        *(short4v*)(dst + ((size_t)b * NN + n) * 32 + 8 * q + 4 * h) = s4;
      }
    }
  }
}

// ---------------- Kernel 2a: partial row stats (S' domain) ----------------
__global__ __launch_bounds__(64) void k_rowstats_part(
    const unsigned short* __restrict__ Qt, const unsigned short* __restrict__ Kt,
    float* __restrict__ pmax, float* __restrict__ psum)
{
  const int l = threadIdx.x, h = l >> 5, col = l & 31;
  const int b = blockIdx.y;
  const int n0 = blockIdx.x * 32;
  const int mbase = blockIdx.z * (NN / MSPLIT);
  const unsigned short* Qb = Qt + (size_t)b * NN * 32;
  const unsigned short* Kb = Kt + (size_t)b * NN * 32;

  bf16x8 aq0 = ld_frag(Qb + (size_t)(n0 + col) * 32 + 8 * h);
  bf16x8 aq1 = ld_frag(Qb + (size_t)(n0 + col) * 32 + 16 + 8 * h);

  float mx[16];
#pragma unroll
  for (int r = 0; r < 16; ++r) mx[r] = -3.4e38f;

  for (int m0 = mbase; m0 < mbase + NN / MSPLIT; m0 += 32) {
    bf16x8 bk0 = ld_frag(Kb + (size_t)(m0 + col) * 32 + 8 * h);
    bf16x8 bk1 = ld_frag(Kb + (size_t)(m0 + col) * 32 + 16 + 8 * h);
    f32x16 S = zero16();
    S = mfma32(aq0, bk0, S);
    S = mfma32(aq1, bk1, S);
#pragma unroll
    for (int r = 0; r < 16; ++r) mx[r] = fmaxf(mx[r], S[r]);
  }
#pragma unroll
  for (int off = 1; off < 32; off <<= 1)
#pragma unroll
    for (int r = 0; r < 16; ++r) mx[r] = fmaxf(mx[r], __shfl_xor(mx[r], off));

  float sm[16];
#pragma unroll
  for (int r = 0; r < 16; ++r) sm[r] = 0.0f;

  for (int m0 = mbase; m0 < mbase + NN / MSPLIT; m0 += 32) {
    bf16x8 bk0 = ld_frag(Kb + (size_t)(m0 + col) * 32 + 8 * h);
    bf16x8 bk1 = ld_frag(Kb + (size_t)(m0 + col) * 32 + 16 + 8 * h);
    f32x16 S = zero16();
    S = mfma32(aq0, bk0, S);
    S = mfma32(aq1, bk1, S);
#pragma unroll
    for (int r = 0; r < 16; ++r) sm[r] += __builtin_amdgcn_exp2f(S[r] - mx[r]);
  }
#pragma unroll
  for (int off = 1; off < 32; off <<= 1)
#pragma unroll
    for (int r = 0; r < 16; ++r) sm[r] += __shfl_xor(sm[r], off);

  if (col == 0) {
    const size_t base = ((size_t)b * MSPLIT + blockIdx.z) * NN;
#pragma unroll
    for (int r = 0; r < 16; ++r) {
      int n = n0 + (r & 3) + 8 * (r >> 2) + 4 * h;
      pmax[base + n] = mx[r];
      psum[base + n] = sm[r];
    }
  }
}

// ---------------- Kernel 2b: combine -> cbias = -max' - log2(sum) ---------
__global__ __launch_bounds__(256) void k_statfin(
    const float* __restrict__ pmax, const float* __restrict__ psum,
    float* __restrict__ cbias)
{
  const int i = blockIdx.x * 256 + threadIdx.x;
  const int b = i >> 12, n = i & (NN - 1);
  float pm[MSPLIT], ps[MSPLIT];
#pragma unroll
  for (int s = 0; s < MSPLIT; ++s) {
    pm[s] = pmax[((size_t)b * MSPLIT + s) * NN + n];
    ps[s] = psum[((size_t)b * MSPLIT + s) * NN + n];
  }
  float gmax = pm[0];
#pragma unroll
  for (int s = 1; s < MSPLIT; ++s) gmax = fmaxf(gmax, pm[s]);
  float gsum = 0.0f;
#pragma unroll
  for (int s = 0; s < MSPLIT; ++s) gsum += ps[s] * __builtin_amdgcn_exp2f(pm[s] - gmax);
  cbias[i] = -gmax - __builtin_amdgcn_logf(gsum);
}

// ---------------- Kernel 3: V @ E (n-split partials, reg-pipelined) -------
// grid 256*nsplit (XCD-swizzled), 4 waves. Wave: ch=w&1 (128 c), mf=w>>1.
__global__ __launch_bounds__(256) void k_attn_out(
    const unsigned short* __restrict__ Qt, const unsigned short* __restrict__ Kt,
    const unsigned short* __restrict__ Vb,
    const float* __restrict__ cbias,
    const float* __restrict__ x, const float* __restrict__ gamma,
    float* __restrict__ out, float* __restrict__ pout,
    int nsplit, int nlen)
{
  const int wg = (int)blockIdx.x;
  const int chunk = (int)gridDim.x >> 3;           // blocks per XCD (bijective)
  const int id2 = (wg & 7) * chunk + (wg >> 3);
  const int per_b = 64 * nsplit;
  const int b = id2 / per_b;
  const int rem = id2 - b * per_b;
  const int ns = rem >> 6;
  const int m0 = (rem & 63) * 64;
  const int nbeg = ns * nlen;

  const int t = threadIdx.x;
  const int w = t >> 6, l = t & 63, h = l >> 5, col = l & 31;
  const int ch = w & 1, mf = w >> 1;
  const int cbase = 128 * ch;
  const int m = m0 + 32 * mf + col;

  const unsigned short* Qb  = Qt + (size_t)b * NN * 32;
  const unsigned short* Kb  = Kt + (size_t)b * NN * 32;
  const unsigned short* Vbb = Vb + (size_t)b * CC * NN;
  const float* cb = cbias + (size_t)b * NN;

  bf16x8 bk0 = ld_frag(Kb + (size_t)m * 32 + 8 * h);
  bf16x8 bk1 = ld_frag(Kb + (size_t)m * 32 + 16 + 8 * h);

  const unsigned short* vr0 = Vbb + (size_t)(cbase + col) * NN;
  const unsigned short* vr1 = vr0 + (size_t)32 * NN;
  const unsigned short* vr2 = vr1 + (size_t)32 * NN;
  const unsigned short* vr3 = vr2 + (size_t)32 * NN;

  f32x16 acc[4];
#pragma unroll
  for (int cf = 0; cf < 4; ++cf) acc[cf] = zero16();

  const int iters = nlen >> 5;
  // prime the Q pipeline
  bf16x8 aq0c = ld_frag(Qb + (size_t)(nbeg + col) * 32 + 8 * h);
  bf16x8 aq1c = ld_frag(Qb + (size_t)(nbeg + col) * 32 + 16 + 8 * h);

  for (int it = 0; it < iters; ++it) {
    const int nn = nbeg + (it << 5);
    const int nx = (it + 1 < iters) ? nn + 32 : nbeg;   // wrap: harmless reload

    // --- issue phase: next-iter Q, current V, current cbias ---------------
    bf16x8 aq0n = ld_frag(Qb + (size_t)(nx + col) * 32 + 8 * h);
    bf16x8 aq1n = ld_frag(Qb + (size_t)(nx + col) * 32 + 16 + 8 * h);
    bf16x8 av00 = ld_frag(vr0 + nn + 8 * h);
    bf16x8 av01 = ld_frag(vr0 + nn + 16 + 8 * h);
    bf16x8 av10 = ld_frag(vr1 + nn + 8 * h);
    bf16x8 av11 = ld_frag(vr1 + nn + 16 + 8 * h);
    bf16x8 av20 = ld_frag(vr2 + nn + 8 * h);
    bf16x8 av21 = ld_frag(vr2 + nn + 16 + 8 * h);
    bf16x8 av30 = ld_frag(vr3 + nn + 8 * h);
    bf16x8 av31 = ld_frag(vr3 + nn + 16 + 8 * h);
    f32x4 cb4[4];
#pragma unroll
    for (int q = 0; q < 4; ++q) cb4[q] = *(const f32x4*)(cb + nn + 8 * q + 4 * h);

    // --- S = Q'^T K (registers only) --------------------------------------
    f32x16 S = zero16();
    S = mfma32(aq0c, bk0, S);
    S = mfma32(aq1c, bk1, S);

    // --- E = exp2(S' + cbias[n]); pack to bf16 ----------------------------
    PackU p0, p1;
#pragma unroll
    for (int q = 0; q < 4; ++q) {
#pragma unroll
      for (int i = 0; i < 4; ++i) {
        float e = __builtin_amdgcn_exp2f(S[4 * q + i] + cb4[q][i]);
        if (q < 2) p0.h[4 * q + i] = (__bf16)e;
        else       p1.h[4 * (q - 2) + i] = (__bf16)e;
      }
    }
    // relayout: swap(u[0],u[2]) -> (W0,W2); swap(u[1],u[3]) -> (W1,W3)
    unsigned e00 = p0.u[0], e02 = p0.u[2];
    unsigned e01 = p0.u[1], e03 = p0.u[3];
    unsigned e10 = p1.u[0], e12 = p1.u[2];
    unsigned e11 = p1.u[1], e13 = p1.u[3];
    asm("v_permlane32_swap_b32 %0, %1" : "+v"(e00), "+v"(e02));
    asm("v_permlane32_swap_b32 %0, %1" : "+v"(e01), "+v"(e03));
    asm("v_permlane32_swap_b32 %0, %1" : "+v"(e10), "+v"(e12));
    asm("v_permlane32_swap_b32 %0, %1" : "+v"(e11), "+v"(e13));
    FragU be0, be1;
    be0.u[0] = e00; be0.u[1] = e01; be0.u[2] = e02; be0.u[3] = e03;
    be1.u[0] = e10; be1.u[1] = e11; be1.u[2] = e12; be1.u[3] = e13;

    // --- PV: V loads were issued ~whole chain ago -------------------------
    acc[0] = mfma32(av00, be0.b, acc[0]);
    acc[0] = mfma32(av01, be1.b, acc[0]);
    acc[1] = mfma32(av10, be0.b, acc[1]);
    acc[1] = mfma32(av11, be1.b, acc[1]);
    acc[2] = mfma32(av20, be0.b, acc[2]);
    acc[2] = mfma32(av21, be1.b, acc[2]);
    acc[3] = mfma32(av30, be0.b, acc[3]);
    acc[3] = mfma32(av31, be1.b, acc[3]);

    aq0c = aq0n; aq1c = aq1n;
  }

  if (pout) {
    float* pb = pout + ((size_t)ns * NB + b) * CC * NN;
#pragma unroll
    for (int cf = 0; cf < 4; ++cf)
#pragma unroll
      for (int r = 0; r < 16; ++r) {
        int c = cbase + 32 * cf + (r & 3) + 8 * (r >> 2) + 4 * h;
        pb[(size_t)c * NN + m] = acc[cf][r];
      }
  } else {
    const float g = gamma[0];
#pragma unroll
    for (int cf = 0; cf < 4; ++cf)
#pragma unroll
      for (int r = 0; r < 16; ++r) {
        int c = cbase + 32 * cf + (r & 3) + 8 * (r >> 2) + 4 * h;
        size_t idx = ((size_t)b * CC + c) * NN + m;
        out[idx] = g * acc[cf][r] + x[idx];
      }
  }
}

// ---------------- Kernel 4: combine partials ------------------------------
__global__ __launch_bounds__(256) void k_comb(
    const float* __restrict__ pout, const float* __restrict__ x,
    const float* __restrict__ gamma, float* __restrict__ out, int nsplit)
{
  const size_t STRIDE = (size_t)NB * CC * NN;
  const size_t i = ((size_t)blockIdx.x * 256 + threadIdx.x) * 4;
  f32x4 s = *(const f32x4*)(pout + i);
  for (int ns = 1; ns < nsplit; ++ns) {
    f32x4 p = *(const f32x4*)(pout + ns * STRIDE + i);
#pragma unroll
    for (int j = 0; j < 4; ++j) s[j] += p[j];
  }
  const float g = gamma[0];
  f32x4 xv = *(const f32x4*)(x + i);
  f32x4 o;
#pragma unroll
  for (int j = 0; j < 4; ++j) o[j] = g * s[j] + xv[j];
  *(f32x4*)(out + i) = o;
}

// ---------------- launch ---------------------------------------------------
extern "C" void kernel_launch(void* const* d_in, const int* in_sizes, int n_in,
                              void* d_out, int out_size, void* d_ws, size_t ws_size,
                              hipStream_t stream) {
  const float* x     = (const float*)d_in[0];
  const float* Wq    = (const float*)d_in[1];
  const float* bq    = (const float*)d_in[2];
  const float* Wk    = (const float*)d_in[3];
  const float* bk    = (const float*)d_in[4];
  const float* Wv    = (const float*)d_in[5];
  const float* bv    = (const float*)d_in[6];
  const float* gamma = (const float*)d_in[7];
  float* out = (float*)d_out;

  char* ws = (char*)d_ws;
  unsigned short* Qt = (unsigned short*)(ws);                      // 1 MB
  unsigned short* Kt = (unsigned short*)(ws + (1u << 20));         // 1 MB
  unsigned short* Vb = (unsigned short*)(ws + (2u << 20));         // 8 MB
  float* pmax  = (float*)(ws + (10u << 20));                       // 256 KB
  float* psum  = (float*)(ws + (10u << 20) + (1u << 18));          // 256 KB
  float* cbias = (float*)(ws + (10u << 20) + (2u << 18));          // 64 KB
  const size_t POUT_OFF = (11u << 20);
  float* pout = (float*)(ws + POUT_OFF);
  const size_t PART_BYTES = (size_t)NB * CC * NN * 4;              // 16 MB

  int nsplit = (ws_size >= POUT_OFF + 2 * PART_BYTES) ? 2 : 1;

  k_proj<<<dim3(NN / 32, NB), 256, 0, stream>>>(x, Wq, bq, Wk, bk, Wv, bv, Qt, Kt, Vb);
  k_rowstats_part<<<dim3(NN / 32, NB, MSPLIT), 64, 0, stream>>>(Qt, Kt, pmax, psum);
  k_statfin<<<dim3(NB * NN / 256), 256, 0, stream>>>(pmax, psum, cbias);

  if (nsplit > 1) {
    k_attn_out<<<dim3(256 * nsplit), 256, 0, stream>>>(
        Qt, Kt, Vb, cbias, x, gamma, out, pout, nsplit, NN / nsplit);
    k_comb<<<dim3(NB * CC * NN / 1024), 256, 0, stream>>>(pout, x, gamma, out, nsplit);
  } else {
    k_attn_out<<<dim3(256), 256, 0, stream>>>(
        Qt, Kt, Vb, cbias, x, gamma, out, nullptr, 1, NN);
  }
}

// Round 5
// 152.890 us; speedup vs baseline: 1.6164x; 1.4561x over previous
//
#include <hip/hip_runtime.h>
#include <hip/hip_bf16.h>

// attention_11269994185437: B=4, C=256, CQK=32, H=W=64 -> N=4096
// out = gamma * (V @ P) + x,  P[n,m] = softmax over m of S[n,m], S = Q^T K.
// Qt pre-scaled by L2E: S' = L2E*S. cbias[b][n] = -max(S') - log2(sum exp2(S'-max)).
// k_attn_out computes out^T = E^T * V^T:
//   - be (B-frag of E) reused as A-frag of E^T (identical lane mapping)
//   - V stored k-tiled Vt[b][n/16][c][16] so V^T B-frags are 1KB coalesced loads
//   - D-tile (lane=c, row=m) stored to pout[ns][b][m][c] coalesced
// k_comb: sum partials, LDS-transpose [m][c]->[c][m], out = g*sum + x.

#define NB 4
#define CC 256
#define NN 4096
#define MSPLIT 4
#define L2E 1.44269504088896340f

typedef short  short4v  __attribute__((ext_vector_type(4)));
typedef short  short8v  __attribute__((ext_vector_type(8)));
typedef __bf16 bf16x8   __attribute__((ext_vector_type(8)));
typedef float  f32x4    __attribute__((ext_vector_type(4)));
typedef float  f32x16   __attribute__((ext_vector_type(16)));

static __device__ __forceinline__ unsigned short f2bf(float f) {
  union { __bf16 h; unsigned short u; } v; v.h = (__bf16)f; return v.u;
}

union FragU { short8v s; bf16x8 b; unsigned u[4]; };
union PackU { __bf16 h[8]; unsigned u[4]; };

static __device__ __forceinline__ bf16x8 ld_frag(const unsigned short* p) {
  FragU u; u.s = *(const short8v*)p; return u.b;
}

static __device__ __forceinline__ f32x16 zero16() {
  f32x16 v;
#pragma unroll
  for (int i = 0; i < 16; ++i) v[i] = 0.0f;
  return v;
}

static __device__ __forceinline__ f32x16 mfma32(bf16x8 a, bf16x8 b, f32x16 c) {
  return __builtin_amdgcn_mfma_f32_32x32x16_bf16(a, b, c, 0, 0, 0);
}

// ---------------- Kernel 1: QKV projection --------------------------------
// grid (N/32, B), block 256 (4 waves). Frags f: 0->Q, 1->K, 2..9->V rows.
__global__ __launch_bounds__(256) void k_proj(
    const float* __restrict__ x,
    const float* __restrict__ Wq, const float* __restrict__ bq,
    const float* __restrict__ Wk, const float* __restrict__ bk,
    const float* __restrict__ Wv, const float* __restrict__ bv,
    unsigned short* __restrict__ Qt, unsigned short* __restrict__ Kt,
    unsigned short* __restrict__ Vt)
{
  __shared__ unsigned short xs[32][268];   // xs[n_local][c]
  const int t = threadIdx.x;
  const int b = blockIdx.y;
  const int n0 = blockIdx.x * 32;
  const int w = t >> 6, l = t & 63, h = l >> 5, col = l & 31;

  const float* xb = x + (size_t)b * CC * NN;
  {
    const int c_off = t >> 3, nl = 4 * (t & 7);
#pragma unroll
    for (int c0 = 0; c0 < CC; c0 += 32) {
      int c = c0 + c_off;
      f32x4 v4 = *(const f32x4*)(xb + (size_t)c * NN + n0 + nl);
#pragma unroll
      for (int j = 0; j < 4; ++j) xs[nl + j][c] = f2bf(v4[j]);
    }
  }
  __syncthreads();

  for (int f = w; f < 10; f += 4) {
    const float* Wsrc; const float* bsrc; int rowbase; int mode;
    if (f == 0)      { Wsrc = Wq; bsrc = bq; rowbase = 0;            mode = 0; }
    else if (f == 1) { Wsrc = Wk; bsrc = bk; rowbase = 0;            mode = 1; }
    else             { Wsrc = Wv; bsrc = bv; rowbase = (f - 2) * 32; mode = 2; }

    f32x16 acc0 = zero16();
    const float* wr = Wsrc + (size_t)(rowbase + col) * CC + 8 * h;

#pragma unroll
    for (int k0 = 0; k0 < CC; k0 += 16) {
      f32x4 w0 = *(const f32x4*)(wr + k0);
      f32x4 w1 = *(const f32x4*)(wr + k0 + 4);
      FragU a;
#pragma unroll
      for (int j = 0; j < 4; ++j) { a.s[j] = (short)f2bf(w0[j]); a.s[4 + j] = (short)f2bf(w1[j]); }
      const unsigned short* p0 = &xs[col][k0 + 8 * h];
      FragU b0;
      short4v t0a = *(const short4v*)p0, t0b = *(const short4v*)(p0 + 4);
#pragma unroll
      for (int j = 0; j < 4; ++j) { b0.s[j] = t0a[j]; b0.s[4 + j] = t0b[j]; }
      acc0 = mfma32(a.b, b0.b, acc0);
    }

    const int n = n0 + col;
#pragma unroll
    for (int q = 0; q < 4; ++q) {
      f32x4 bias4 = *(const f32x4*)(bsrc + rowbase + 8 * q + 4 * h);
      float vals[4];
#pragma unroll
      for (int i = 0; i < 4; ++i) vals[i] = acc0[4 * q + i] + bias4[i];
      if (mode == 2) {
        // Vt[b][n>>4][c][n&15]
        const size_t tb = ((size_t)b * (NN >> 4) + (n >> 4)) * CC * 16 + (n & 15);
#pragma unroll
        for (int i = 0; i < 4; ++i) {
          int c = rowbase + 8 * q + 4 * h + i;
          Vt[tb + (size_t)c * 16] = f2bf(vals[i]);
        }
      } else {
        unsigned short* dst = (mode == 0) ? Qt : Kt;
        const float scale = (mode == 0) ? L2E : 1.0f;   // fold L2E into Q
        short4v s4;
#pragma unroll
        for (int i = 0; i < 4; ++i) s4[i] = (short)f2bf(vals[i] * scale);
        *(short4v*)(dst + ((size_t)b * NN + n) * 32 + 8 * q + 4 * h) = s4;
      }
    }
  }
}

// ---------------- Kernel 2a: partial row stats (S' domain) ----------------
// grid (N/32, B, MSPLIT), block 256 (4 waves; wave w covers 256 m), LDS merge.
__global__ __launch_bounds__(256) void k_rowstats_part(
    const unsigned short* __restrict__ Qt, const unsigned short* __restrict__ Kt,
    float* __restrict__ pmax, float* __restrict__ psum)
{
  __shared__ float smax[4][32], ssum[4][32];
  const int t = threadIdx.x;
  const int w = t >> 6, l = t & 63, h = l >> 5, col = l & 31;
  const int b = blockIdx.y;
  const int n0 = blockIdx.x * 32;
  const int mlen = NN / MSPLIT / 4;                 // 256
  const int mbase = blockIdx.z * (NN / MSPLIT) + w * mlen;
  const unsigned short* Qb = Qt + (size_t)b * NN * 32;
  const unsigned short* Kb = Kt + (size_t)b * NN * 32;

  bf16x8 aq0 = ld_frag(Qb + (size_t)(n0 + col) * 32 + 8 * h);
  bf16x8 aq1 = ld_frag(Qb + (size_t)(n0 + col) * 32 + 16 + 8 * h);

  float mx[16];
#pragma unroll
  for (int r = 0; r < 16; ++r) mx[r] = -3.4e38f;

  for (int m0 = mbase; m0 < mbase + mlen; m0 += 32) {
    bf16x8 bk0 = ld_frag(Kb + (size_t)(m0 + col) * 32 + 8 * h);
    bf16x8 bk1 = ld_frag(Kb + (size_t)(m0 + col) * 32 + 16 + 8 * h);
    f32x16 S = zero16();
    S = mfma32(aq0, bk0, S);
    S = mfma32(aq1, bk1, S);
#pragma unroll
    for (int r = 0; r < 16; ++r) mx[r] = fmaxf(mx[r], S[r]);
  }
#pragma unroll
  for (int off = 1; off < 32; off <<= 1)
#pragma unroll
    for (int r = 0; r < 16; ++r) mx[r] = fmaxf(mx[r], __shfl_xor(mx[r], off));

  float sm[16];
#pragma unroll
  for (int r = 0; r < 16; ++r) sm[r] = 0.0f;

  for (int m0 = mbase; m0 < mbase + mlen; m0 += 32) {
    bf16x8 bk0 = ld_frag(Kb + (size_t)(m0 + col) * 32 + 8 * h);
    bf16x8 bk1 = ld_frag(Kb + (size_t)(m0 + col) * 32 + 16 + 8 * h);
    f32x16 S = zero16();
    S = mfma32(aq0, bk0, S);
    S = mfma32(aq1, bk1, S);
#pragma unroll
    for (int r = 0; r < 16; ++r) sm[r] += __builtin_amdgcn_exp2f(S[r] - mx[r]);
  }
#pragma unroll
  for (int off = 1; off < 32; off <<= 1)
#pragma unroll
    for (int r = 0; r < 16; ++r) sm[r] += __shfl_xor(sm[r], off);

  if (col == 0) {
#pragma unroll
    for (int r = 0; r < 16; ++r) {
      int nl = (r & 3) + 8 * (r >> 2) + 4 * h;
      smax[w][nl] = mx[r];
      ssum[w][nl] = sm[r];
    }
  }
  __syncthreads();

  if (t < 32) {
    float gm = smax[0][t];
#pragma unroll
    for (int wv = 1; wv < 4; ++wv) gm = fmaxf(gm, smax[wv][t]);
    float s = 0.0f;
#pragma unroll
    for (int wv = 0; wv < 4; ++wv)
      s += ssum[wv][t] * __builtin_amdgcn_exp2f(smax[wv][t] - gm);
    const size_t base = ((size_t)b * MSPLIT + blockIdx.z) * NN;
    pmax[base + n0 + t] = gm;
    psum[base + n0 + t] = s;
  }
}

// ---------------- Kernel 2b: combine -> cbias = -max' - log2(sum) ---------
__global__ __launch_bounds__(256) void k_statfin(
    const float* __restrict__ pmax, const float* __restrict__ psum,
    float* __restrict__ cbias)
{
  const int i = blockIdx.x * 256 + threadIdx.x;
  const int b = i >> 12, n = i & (NN - 1);
  float pm[MSPLIT], ps[MSPLIT];
#pragma unroll
  for (int s = 0; s < MSPLIT; ++s) {
    pm[s] = pmax[((size_t)b * MSPLIT + s) * NN + n];
    ps[s] = psum[((size_t)b * MSPLIT + s) * NN + n];
  }
  float gmax = pm[0];
#pragma unroll
  for (int s = 1; s < MSPLIT; ++s) gmax = fmaxf(gmax, pm[s]);
  float gsum = 0.0f;
#pragma unroll
  for (int s = 0; s < MSPLIT; ++s) gsum += ps[s] * __builtin_amdgcn_exp2f(pm[s] - gmax);
  cbias[i] = -gmax - __builtin_amdgcn_logf(gsum);
}

// ---------------- Kernel 3: out^T = E^T * V^T (n-split partials) ----------
// grid 256*nsplit (XCD-swizzled), 4 waves. Wave: ch=w&1 (128 c), mf=w>>1 (32 m).
__global__ __launch_bounds__(256) void k_attn_out(
    const unsigned short* __restrict__ Qt, const unsigned short* __restrict__ Kt,
    const unsigned short* __restrict__ Vt,
    const float* __restrict__ cbias,
    float* __restrict__ pout,
    int nsplit, int nlen)
{
  const int wg = (int)blockIdx.x;
  const int chunk = (int)gridDim.x >> 3;           // blocks per XCD (bijective)
  const int id2 = (wg & 7) * chunk + (wg >> 3);
  const int per_b = 64 * nsplit;
  const int b = id2 / per_b;
  const int rem = id2 - b * per_b;
  const int ns = rem >> 6;
  const int m0 = (rem & 63) * 64;
  const int nbeg = ns * nlen;

  const int t = threadIdx.x;
  const int w = t >> 6, l = t & 63, h = l >> 5, col = l & 31;
  const int ch = w & 1, mf = w >> 1;
  const int cbase = 128 * ch;
  const int m = m0 + 32 * mf + col;

  const unsigned short* Qb  = Qt + (size_t)b * NN * 32;
  const unsigned short* Kb  = Kt + (size_t)b * NN * 32;
  const unsigned short* Vtb = Vt + (size_t)b * (NN >> 4) * CC * 16;
  const float* cb = cbias + (size_t)b * NN;

  bf16x8 bk0 = ld_frag(Kb + (size_t)m * 32 + 8 * h);
  bf16x8 bk1 = ld_frag(Kb + (size_t)m * 32 + 16 + 8 * h);

  f32x16 acc[4];
#pragma unroll
  for (int cf = 0; cf < 4; ++cf) acc[cf] = zero16();

  const int iters = nlen >> 5;
  bf16x8 aq0c = ld_frag(Qb + (size_t)(nbeg + col) * 32 + 8 * h);
  bf16x8 aq1c = ld_frag(Qb + (size_t)(nbeg + col) * 32 + 16 + 8 * h);

  for (int it = 0; it < iters; ++it) {
    const int nn = nbeg + (it << 5);
    const int nx = (it + 1 < iters) ? nn + 32 : nbeg;

    // --- issue phase: next-iter Q, current V^T tiles, current cbias -------
    bf16x8 aq0n = ld_frag(Qb + (size_t)(nx + col) * 32 + 8 * h);
    bf16x8 aq1n = ld_frag(Qb + (size_t)(nx + col) * 32 + 16 + 8 * h);
    // V^T B-frags: Vt[(nn>>4)+kh][cbase+32cf+col][8h..8h+7] -- 1KB coalesced
    const unsigned short* vt0 = Vtb + (((size_t)(nn >> 4)) * CC + cbase + col) * 16 + 8 * h;
    const unsigned short* vt1 = vt0 + (size_t)CC * 16;
    bf16x8 bv00 = ld_frag(vt0);
    bf16x8 bv01 = ld_frag(vt0 + 32 * 16);
    bf16x8 bv02 = ld_frag(vt0 + 64 * 16);
    bf16x8 bv03 = ld_frag(vt0 + 96 * 16);
    bf16x8 bv10 = ld_frag(vt1);
    bf16x8 bv11 = ld_frag(vt1 + 32 * 16);
    bf16x8 bv12 = ld_frag(vt1 + 64 * 16);
    bf16x8 bv13 = ld_frag(vt1 + 96 * 16);
    f32x4 cb4[4];
#pragma unroll
    for (int q = 0; q < 4; ++q) cb4[q] = *(const f32x4*)(cb + nn + 8 * q + 4 * h);

    // --- S' = Q'^T K ------------------------------------------------------
    f32x16 S = zero16();
    S = mfma32(aq0c, bk0, S);
    S = mfma32(aq1c, bk1, S);

    // --- E = exp2(S' + cbias[n]); pack to bf16 ----------------------------
    PackU p0, p1;
#pragma unroll
    for (int q = 0; q < 4; ++q) {
#pragma unroll
      for (int i = 0; i < 4; ++i) {
        float e = __builtin_amdgcn_exp2f(S[4 * q + i] + cb4[q][i]);
        if (q < 2) p0.h[4 * q + i] = (__bf16)e;
        else       p1.h[4 * (q - 2) + i] = (__bf16)e;
      }
    }
    // relayout: swap(u[0],u[2]) -> (W0,W2); swap(u[1],u[3]) -> (W1,W3)
    unsigned e00 = p0.u[0], e02 = p0.u[2];
    unsigned e01 = p0.u[1], e03 = p0.u[3];
    unsigned e10 = p1.u[0], e12 = p1.u[2];
    unsigned e11 = p1.u[1], e13 = p1.u[3];
    asm("v_permlane32_swap_b32 %0, %1" : "+v"(e00), "+v"(e02));
    asm("v_permlane32_swap_b32 %0, %1" : "+v"(e01), "+v"(e03));
    asm("v_permlane32_swap_b32 %0, %1" : "+v"(e10), "+v"(e12));
    asm("v_permlane32_swap_b32 %0, %1" : "+v"(e11), "+v"(e13));
    FragU be0, be1;   // B-frag of E == A-frag of E^T (identical lane mapping)
    be0.u[0] = e00; be0.u[1] = e01; be0.u[2] = e02; be0.u[3] = e03;
    be1.u[0] = e10; be1.u[1] = e11; be1.u[2] = e12; be1.u[3] = e13;

    // --- out^T += E^T[m][n] * V^T[n][c] -----------------------------------
    acc[0] = mfma32(be0.b, bv00, acc[0]);
    acc[0] = mfma32(be1.b, bv10, acc[0]);
    acc[1] = mfma32(be0.b, bv01, acc[1]);
    acc[1] = mfma32(be1.b, bv11, acc[1]);
    acc[2] = mfma32(be0.b, bv02, acc[2]);
    acc[2] = mfma32(be1.b, bv12, acc[2]);
    acc[3] = mfma32(be0.b, bv03, acc[3]);
    acc[3] = mfma32(be1.b, bv13, acc[3]);

    aq0c = aq0n; aq1c = aq1n;
  }

  // D-tile: row = m_local = crow(r,h), col = c. Store [m][c]-major: coalesced.
  float* pb = pout + (((size_t)ns * NB + b) * NN + (size_t)(m0 + 32 * mf)) * CC + cbase;
#pragma unroll
  for (int cf = 0; cf < 4; ++cf)
#pragma unroll
    for (int r = 0; r < 16; ++r) {
      int mloc = (r & 3) + 8 * (r >> 2) + 4 * h;
      pb[(size_t)mloc * CC + 32 * cf + col] = acc[cf][r];
    }
}

// ---------------- Kernel 4: combine + transpose + residual ----------------
// grid (NN/64, CC/64, NB), block 256. pout[ns][b][m][c] -> out[b][c][m].
__global__ __launch_bounds__(256) void k_comb(
    const float* __restrict__ pout, const float* __restrict__ x,
    const float* __restrict__ gamma, float* __restrict__ out, int nsplit)
{
  __shared__ float ld[64][65];
  const size_t STRIDE = (size_t)NB * CC * NN;
  const int t = threadIdx.x;
  const int m0 = blockIdx.x * 64, c0 = blockIdx.y * 64, b = blockIdx.z;
  const int ci = t & 63, mo = t >> 6;

  const float* pb = pout + ((size_t)b * NN + m0) * CC + c0;
#pragma unroll
  for (int rep = 0; rep < 16; ++rep) {
    const int mi = 4 * rep + mo;
    float s = pb[(size_t)mi * CC + ci];
    for (int ns = 1; ns < nsplit; ++ns)
      s += pb[ns * STRIDE + (size_t)mi * CC + ci];
    ld[mi][ci] = s;
  }
  __syncthreads();

  const float g = gamma[0];
  const int mi2 = t & 63;
#pragma unroll
  for (int rep = 0; rep < 16; ++rep) {
    const int cj = 4 * rep + mo;
    const size_t idx = ((size_t)b * CC + c0 + cj) * NN + m0 + mi2;
    out[idx] = g * ld[mi2][cj] + x[idx];
  }
}

// ---------------- launch ---------------------------------------------------
extern "C" void kernel_launch(void* const* d_in, const int* in_sizes, int n_in,
                              void* d_out, int out_size, void* d_ws, size_t ws_size,
                              hipStream_t stream) {
  const float* x     = (const float*)d_in[0];
  const float* Wq    = (const float*)d_in[1];
  const float* bq    = (const float*)d_in[2];
  const float* Wk    = (const float*)d_in[3];
  const float* bk    = (const float*)d_in[4];
  const float* Wv    = (const float*)d_in[5];
  const float* bv    = (const float*)d_in[6];
  const float* gamma = (const float*)d_in[7];
  float* out = (float*)d_out;

  char* ws = (char*)d_ws;
  unsigned short* Qt = (unsigned short*)(ws);                      // 1 MB
  unsigned short* Kt = (unsigned short*)(ws + (1u << 20));         // 1 MB
  unsigned short* Vt = (unsigned short*)(ws + (2u << 20));         // 8 MB
  float* pmax  = (float*)(ws + (10u << 20));                       // 256 KB
  float* psum  = (float*)(ws + (10u << 20) + (1u << 18));          // 256 KB
  float* cbias = (float*)(ws + (10u << 20) + (2u << 18));          // 64 KB
  const size_t POUT_OFF = (11u << 20);
  float* pout = (float*)(ws + POUT_OFF);
  const size_t PART_BYTES = (size_t)NB * CC * NN * 4;              // 16 MB

  int nsplit = (ws_size >= POUT_OFF + 2 * PART_BYTES) ? 2 : 1;

  k_proj<<<dim3(NN / 32, NB), 256, 0, stream>>>(x, Wq, bq, Wk, bk, Wv, bv, Qt, Kt, Vt);
  k_rowstats_part<<<dim3(NN / 32, NB, MSPLIT), 256, 0, stream>>>(Qt, Kt, pmax, psum);
  k_statfin<<<dim3(NB * NN / 256), 256, 0, stream>>>(pmax, psum, cbias);
  k_attn_out<<<dim3(256 * nsplit), 256, 0, stream>>>(
      Qt, Kt, Vt, cbias, pout, nsplit, NN / nsplit);
  k_comb<<<dim3(NN / 64, CC / 64, NB), 256, 0, stream>>>(pout, x, gamma, out, nsplit);
}